// Round 1
// baseline (1145.567 us; speedup 1.0000x reference)
//
#include <hip/hip_runtime.h>
#include <math.h>

#define H_ 192
#define W_ 384
#define HW_ 73728
#define NB_ 2
#define NPIX_ 147456   // NB_*HW_, divisible by 256 -> 576 blocks

// ---------------------------------------------------------------------------
// K1: x-projections.  x [2,64,H,W] -> x1,x2 [2,16,H,W], x3 [2,64,H,W]
// ---------------------------------------------------------------------------
__global__ __launch_bounds__(256) void k_proj_x(
    const float* __restrict__ x,
    const float* __restrict__ wq, const float* __restrict__ bq,
    const float* __restrict__ wk, const float* __restrict__ bk,
    const float* __restrict__ wv, const float* __restrict__ bv,
    float* __restrict__ x1, float* __restrict__ x2, float* __restrict__ x3)
{
    __shared__ float l[1024 + 1024 + 4096 + 96];
    float* lq  = l;
    float* lk  = l + 1024;
    float* lv  = l + 2048;
    float* lbq = l + 6144;
    float* lbk = l + 6160;
    float* lbv = l + 6176;
    for (int i = threadIdx.x; i < 1024; i += 256) { lq[i] = wq[i]; lk[i] = wk[i]; }
    for (int i = threadIdx.x; i < 4096; i += 256) { lv[i] = wv[i]; }
    if (threadIdx.x < 16) { lbq[threadIdx.x] = bq[threadIdx.x]; lbk[threadIdx.x] = bk[threadIdx.x]; }
    if (threadIdx.x < 64) { lbv[threadIdx.x] = bv[threadIdx.x]; }
    __syncthreads();

    int p = blockIdx.x * 256 + threadIdx.x;
    int n = p / HW_, s = p - n * HW_;

    float aq[16], ak[16], av[64];
#pragma unroll
    for (int o = 0; o < 16; o++) { aq[o] = lbq[o]; ak[o] = lbk[o]; }
#pragma unroll
    for (int o = 0; o < 64; o++) { av[o] = lbv[o]; }

    const float* xp = x + n * (64 * HW_) + s;
    for (int c = 0; c < 64; c++) {
        float xv = xp[c * HW_];
#pragma unroll
        for (int o = 0; o < 16; o++) {
            aq[o] = fmaf(lq[o * 64 + c], xv, aq[o]);
            ak[o] = fmaf(lk[o * 64 + c], xv, ak[o]);
        }
#pragma unroll
        for (int o = 0; o < 64; o++) {
            av[o] = fmaf(lv[o * 64 + c], xv, av[o]);
        }
    }
#pragma unroll
    for (int o = 0; o < 16; o++) {
        x1[(n * 16 + o) * HW_ + s] = aq[o];
        x2[(n * 16 + o) * HW_ + s] = ak[o];
    }
#pragma unroll
    for (int o = 0; o < 64; o++) {
        x3[(n * 64 + o) * HW_ + s] = av[o];
    }
}

// ---------------------------------------------------------------------------
// K2: g-projection.  g [2,128,H,W] -> gg [2,16,H,W]
// ---------------------------------------------------------------------------
__global__ __launch_bounds__(256) void k_proj_g(
    const float* __restrict__ g,
    const float* __restrict__ wg, const float* __restrict__ bg,
    float* __restrict__ gg)
{
    __shared__ float l[2048 + 16];
    for (int i = threadIdx.x; i < 2048; i += 256) l[i] = wg[i];
    if (threadIdx.x < 16) l[2048 + threadIdx.x] = bg[threadIdx.x];
    __syncthreads();

    int p = blockIdx.x * 256 + threadIdx.x;
    int n = p / HW_, s = p - n * HW_;

    float a[16];
#pragma unroll
    for (int o = 0; o < 16; o++) a[o] = l[2048 + o];

    const float* gp = g + n * (128 * HW_) + s;
    for (int c = 0; c < 128; c++) {
        float gv = gp[c * HW_];
#pragma unroll
        for (int o = 0; o < 16; o++) a[o] = fmaf(l[o * 128 + c], gv, a[o]);
    }
#pragma unroll
    for (int o = 0; o < 16; o++) gg[(n * 16 + o) * HW_ + s] = a[o];
}

// ---------------------------------------------------------------------------
// K3: fused attention-weight MLPs + softmaxes + first aggregation.
// One thread per pixel.
// ---------------------------------------------------------------------------
struct BParams {
    const float *x1, *x2, *gg, *x3;
    const float *wp;
    const float *bn1g, *bn1b, *bn1m, *bn1v, *w1a;
    const float *bn2g, *bn2b, *bn2m, *bn2v, *w1b, *b1b;
    const float *bn3g, *bn3b, *bn3m, *bn3v, *w2a, *b2a;
    float *out1, *w2o;
};

__global__ __launch_bounds__(256) void k_attn(BParams P)
{
    __shared__ float ls1[18], lt1[18], lw1a[288];
    __shared__ float ls2[16], lt2[16], lw1b[16];
    __shared__ float ls3[16], lt3[16], lw2a[16];
    __shared__ float lwp[4], lsc[2];

    int t = threadIdx.x;
    if (t < 18) {
        float sc = P.bn1g[t] * rsqrtf(P.bn1v[t] + 1e-5f);
        ls1[t] = sc; lt1[t] = P.bn1b[t] - P.bn1m[t] * sc;
    } else if (t >= 32 && t < 48) {
        int c = t - 32;
        float sc = P.bn2g[c] * rsqrtf(P.bn2v[c] + 1e-5f);
        ls2[c] = sc; lt2[c] = P.bn2b[c] - P.bn2m[c] * sc; lw1b[c] = P.w1b[c];
    } else if (t >= 64 && t < 80) {
        int c = t - 64;
        float sc = P.bn3g[c] * rsqrtf(P.bn3v[c] + 1e-5f);
        ls3[c] = sc; lt3[c] = P.bn3b[c] - P.bn3m[c] * sc; lw2a[c] = P.w2a[c];
    } else if (t >= 96 && t < 100) {
        lwp[t - 96] = P.wp[t - 96];
    } else if (t == 100) {
        lsc[0] = P.b1b[0]; lsc[1] = P.b2a[0];
    }
    for (int i = t; i < 288; i += 256) lw1a[i] = P.w1a[i];
    __syncthreads();

    int p = blockIdx.x * 256 + t;
    int n = p / HW_, s = p - n * HW_;
    int hi = s / W_, wi = s - hi * W_;

    float x1c[16], ggc[16];
#pragma unroll
    for (int c = 0; c < 16; c++) {
        x1c[c] = P.x1[(n * 16 + c) * HW_ + s];
        ggc[c] = P.gg[(n * 16 + c) * HW_ + s];
    }

    int sn[9];
    float w1r[9], w2r[9];

#pragma unroll
    for (int ki = 0; ki < 3; ki++) {
#pragma unroll
        for (int kj = 0; kj < 3; kj++) {
            int k = ki * 3 + kj;
            int hn = hi + ki - 1; hn = (hn < 0) ? -hn : ((hn >= H_) ? 2 * (H_ - 1) - hn : hn);
            int wn = wi + kj - 1; wn = (wn < 0) ? -wn : ((wn >= W_) ? 2 * (W_ - 1) - wn : wn);
            sn[k] = hn * W_ + wn;
            float dlw = (float)(wi - wn) * (2.0f / (W_ - 1));
            float dlh = (float)(hi - hn) * (2.0f / (H_ - 1));

            float h1[16];
#pragma unroll
            for (int o = 0; o < 16; o++) h1[o] = 0.0f;

#pragma unroll
            for (int c = 0; c < 16; c++) {
                float f = x1c[c] - P.x2[(n * 16 + c) * HW_ + sn[k]];
                f = fmaxf(fmaf(f, ls1[c], lt1[c]), 0.0f);
#pragma unroll
                for (int o = 0; o < 16; o++) h1[o] = fmaf(lw1a[o * 18 + c], f, h1[o]);
            }
#pragma unroll
            for (int pc = 0; pc < 2; pc++) {
                float f = lwp[pc * 2 + 0] * dlw + lwp[pc * 2 + 1] * dlh;
                f = fmaxf(fmaf(f, ls1[16 + pc], lt1[16 + pc]), 0.0f);
#pragma unroll
                for (int o = 0; o < 16; o++) h1[o] = fmaf(lw1a[o * 18 + 16 + pc], f, h1[o]);
            }
            float l1 = lsc[0];
#pragma unroll
            for (int o = 0; o < 16; o++) {
                float v = fmaxf(fmaf(h1[o], ls2[o], lt2[o]), 0.0f);
                l1 = fmaf(lw1b[o], v, l1);
            }
            w1r[k] = l1;

            float l2 = lsc[1];
#pragma unroll
            for (int c = 0; c < 16; c++) {
                float f = ggc[c] - P.gg[(n * 16 + c) * HW_ + sn[k]];
                f = fmaxf(fmaf(f, ls3[c], lt3[c]), 0.0f);
                l2 = fmaf(lw2a[c], f, l2);
            }
            w2r[k] = l2;
        }
    }

    // softmax over the 9-neighbor dim, both weight sets
    float m1 = w1r[0], m2 = w2r[0];
#pragma unroll
    for (int k = 1; k < 9; k++) { m1 = fmaxf(m1, w1r[k]); m2 = fmaxf(m2, w2r[k]); }
    float sum1 = 0.0f, sum2 = 0.0f;
#pragma unroll
    for (int k = 0; k < 9; k++) {
        w1r[k] = __expf(w1r[k] - m1); sum1 += w1r[k];
        w2r[k] = __expf(w2r[k] - m2); sum2 += w2r[k];
    }
    float i1 = 1.0f / sum1, i2 = 1.0f / sum2;
#pragma unroll
    for (int k = 0; k < 9; k++) { w1r[k] *= i1; w2r[k] *= i2; }

    // store normalized w2 for the second aggregation
#pragma unroll
    for (int k = 0; k < 9; k++) P.w2o[(n * 9 + k) * HW_ + s] = w2r[k];

    // agg1: out1[c] = sum_k w1[k] * x3[c, neighbor_k]
#pragma unroll 4
    for (int c = 0; c < 64; c++) {
        const float* x3c = P.x3 + (n * 64 + c) * HW_;
        float a = 0.0f;
#pragma unroll
        for (int k = 0; k < 9; k++) a = fmaf(w1r[k], x3c[sn[k]], a);
        P.out1[(n * 64 + c) * HW_ + s] = a;
    }
}

// ---------------------------------------------------------------------------
// K4: second aggregation.  out[c] = sum_k w2[k] * out1[c, neighbor_k]
// blockIdx.y selects a 16-channel slab.
// ---------------------------------------------------------------------------
__global__ __launch_bounds__(256) void k_agg2(
    const float* __restrict__ out1, const float* __restrict__ w2,
    float* __restrict__ out)
{
    int p = blockIdx.x * 256 + threadIdx.x;
    int cb = blockIdx.y;
    int n = p / HW_, s = p - n * HW_;
    int hi = s / W_, wi = s - hi * W_;

    int sn[9];
#pragma unroll
    for (int ki = 0; ki < 3; ki++) {
#pragma unroll
        for (int kj = 0; kj < 3; kj++) {
            int hn = hi + ki - 1; hn = (hn < 0) ? -hn : ((hn >= H_) ? 2 * (H_ - 1) - hn : hn);
            int wn = wi + kj - 1; wn = (wn < 0) ? -wn : ((wn >= W_) ? 2 * (W_ - 1) - wn : wn);
            sn[ki * 3 + kj] = hn * W_ + wn;
        }
    }
    float wv[9];
#pragma unroll
    for (int k = 0; k < 9; k++) wv[k] = w2[(n * 9 + k) * HW_ + s];

#pragma unroll
    for (int ci = 0; ci < 16; ci++) {
        int c = cb * 16 + ci;
        const float* o1c = out1 + (n * 64 + c) * HW_;
        float a = 0.0f;
#pragma unroll
        for (int k = 0; k < 9; k++) a = fmaf(wv[k], o1c[sn[k]], a);
        out[(n * 64 + c) * HW_ + s] = a;
    }
}

// ---------------------------------------------------------------------------
extern "C" void kernel_launch(void* const* d_in, const int* in_sizes, int n_in,
                              void* d_out, int out_size, void* d_ws, size_t ws_size,
                              hipStream_t stream)
{
    const float* x    = (const float*)d_in[0];
    const float* g    = (const float*)d_in[1];
    const float* w_q  = (const float*)d_in[2];
    const float* b_q  = (const float*)d_in[3];
    const float* w_k  = (const float*)d_in[4];
    const float* b_k  = (const float*)d_in[5];
    const float* w_v  = (const float*)d_in[6];
    const float* b_v  = (const float*)d_in[7];
    const float* w_g  = (const float*)d_in[8];
    const float* b_g  = (const float*)d_in[9];
    const float* w_p  = (const float*)d_in[10];
    // d_in[11] = b_p (cancels in center-minus-neighbor subtraction)
    const float* bn1g = (const float*)d_in[12];
    const float* bn1b = (const float*)d_in[13];
    const float* bn1m = (const float*)d_in[14];
    const float* bn1v = (const float*)d_in[15];
    const float* w1a  = (const float*)d_in[16];
    const float* bn2g = (const float*)d_in[17];
    const float* bn2b = (const float*)d_in[18];
    const float* bn2m = (const float*)d_in[19];
    const float* bn2v = (const float*)d_in[20];
    const float* w1b  = (const float*)d_in[21];
    const float* b1b  = (const float*)d_in[22];
    const float* bn3g = (const float*)d_in[23];
    const float* bn3b = (const float*)d_in[24];
    const float* bn3m = (const float*)d_in[25];
    const float* bn3v = (const float*)d_in[26];
    const float* w2a  = (const float*)d_in[27];
    const float* b2a  = (const float*)d_in[28];

    float* ws   = (float*)d_ws;
    float* x1   = ws;                       // 2*16*HW = 2359296 f
    float* x2   = x1 + 2359296;             // 2359296 f
    float* gg   = x2 + 2359296;             // 2359296 f
    float* out1 = gg + 2359296;             // 2*64*HW = 9437184 f
    float* w2b  = out1 + 9437184;           // 2*9*HW = 1327104 f
    float* x3   = (float*)d_out;            // d_out doubles as x3 scratch

    k_proj_x<<<576, 256, 0, stream>>>(x, w_q, b_q, w_k, b_k, w_v, b_v, x1, x2, x3);
    k_proj_g<<<576, 256, 0, stream>>>(g, w_g, b_g, gg);

    BParams P;
    P.x1 = x1; P.x2 = x2; P.gg = gg; P.x3 = x3;
    P.wp = w_p;
    P.bn1g = bn1g; P.bn1b = bn1b; P.bn1m = bn1m; P.bn1v = bn1v; P.w1a = w1a;
    P.bn2g = bn2g; P.bn2b = bn2b; P.bn2m = bn2m; P.bn2v = bn2v; P.w1b = w1b; P.b1b = b1b;
    P.bn3g = bn3g; P.bn3b = bn3b; P.bn3m = bn3m; P.bn3v = bn3v; P.w2a = w2a; P.b2a = b2a;
    P.out1 = out1; P.w2o = w2b;
    k_attn<<<576, 256, 0, stream>>>(P);

    k_agg2<<<dim3(576, 4), 256, 0, stream>>>(out1, w2b, (float*)d_out);
}

// Round 2
// 1034.915 us; speedup vs baseline: 1.1069x; 1.1069x over previous
//
#include <hip/hip_runtime.h>
#include <math.h>

#define H_ 192
#define W_ 384
#define HW_ 73728
#define NPIX_ 147456   // 2*HW_, divisible by 256 -> 576 blocks

// ---------------------------------------------------------------------------
// K1: x-projections.  x [2,64,H,W] -> x1,x2 [2,16,H,W], x3 [2,64,H,W]
// ---------------------------------------------------------------------------
__global__ __launch_bounds__(256) void k_proj_x(
    const float* __restrict__ x,
    const float* __restrict__ wq, const float* __restrict__ bq,
    const float* __restrict__ wk, const float* __restrict__ bk,
    const float* __restrict__ wv, const float* __restrict__ bv,
    float* __restrict__ x1, float* __restrict__ x2, float* __restrict__ x3)
{
    __shared__ float l[1024 + 1024 + 4096 + 96];
    float* lq  = l;
    float* lk  = l + 1024;
    float* lv  = l + 2048;
    float* lbq = l + 6144;
    float* lbk = l + 6160;
    float* lbv = l + 6176;
    for (int i = threadIdx.x; i < 1024; i += 256) { lq[i] = wq[i]; lk[i] = wk[i]; }
    for (int i = threadIdx.x; i < 4096; i += 256) { lv[i] = wv[i]; }
    if (threadIdx.x < 16) { lbq[threadIdx.x] = bq[threadIdx.x]; lbk[threadIdx.x] = bk[threadIdx.x]; }
    if (threadIdx.x < 64) { lbv[threadIdx.x] = bv[threadIdx.x]; }
    __syncthreads();

    int p = blockIdx.x * 256 + threadIdx.x;
    int n = p / HW_, s = p - n * HW_;

    float aq[16], ak[16], av[64];
#pragma unroll
    for (int o = 0; o < 16; o++) { aq[o] = lbq[o]; ak[o] = lbk[o]; }
#pragma unroll
    for (int o = 0; o < 64; o++) { av[o] = lbv[o]; }

    const float* xp = x + n * (64 * HW_) + s;
    for (int c = 0; c < 64; c++) {
        float xv = xp[c * HW_];
#pragma unroll
        for (int o = 0; o < 16; o++) {
            aq[o] = fmaf(lq[o * 64 + c], xv, aq[o]);
            ak[o] = fmaf(lk[o * 64 + c], xv, ak[o]);
        }
#pragma unroll
        for (int o = 0; o < 64; o++) {
            av[o] = fmaf(lv[o * 64 + c], xv, av[o]);
        }
    }
#pragma unroll
    for (int o = 0; o < 16; o++) {
        x1[(n * 16 + o) * HW_ + s] = aq[o];
        x2[(n * 16 + o) * HW_ + s] = ak[o];
    }
#pragma unroll
    for (int o = 0; o < 64; o++) {
        x3[(n * 64 + o) * HW_ + s] = av[o];
    }
}

// ---------------------------------------------------------------------------
// K2: g-projection.  g [2,128,H,W] -> gg [2,16,H,W]
// ---------------------------------------------------------------------------
__global__ __launch_bounds__(256) void k_proj_g(
    const float* __restrict__ g,
    const float* __restrict__ wg, const float* __restrict__ bg,
    float* __restrict__ gg)
{
    __shared__ float l[2048 + 16];
    for (int i = threadIdx.x; i < 2048; i += 256) l[i] = wg[i];
    if (threadIdx.x < 16) l[2048 + threadIdx.x] = bg[threadIdx.x];
    __syncthreads();

    int p = blockIdx.x * 256 + threadIdx.x;
    int n = p / HW_, s = p - n * HW_;

    float a[16];
#pragma unroll
    for (int o = 0; o < 16; o++) a[o] = l[2048 + o];

    const float* gp = g + n * (128 * HW_) + s;
    for (int c = 0; c < 128; c++) {
        float gv = gp[c * HW_];
#pragma unroll
        for (int o = 0; o < 16; o++) a[o] = fmaf(l[o * 128 + c], gv, a[o]);
    }
#pragma unroll
    for (int o = 0; o < 16; o++) gg[(n * 16 + o) * HW_ + s] = a[o];
}

// ---------------------------------------------------------------------------
// K3: attention-weight MLPs + softmaxes ONLY (no aggregation -> low VGPR).
// One thread per pixel. w1 is written aliased into the x1 buffer (each
// thread reads x1 only at its own pixel before writing w1 at its own pixel).
// ---------------------------------------------------------------------------
struct WParams {
    const float *x1, *x2, *gg;
    const float *wp;
    const float *bn1g, *bn1b, *bn1m, *bn1v, *w1a;
    const float *bn2g, *bn2b, *bn2m, *bn2v, *w1b, *b1b;
    const float *bn3g, *bn3b, *bn3m, *bn3v, *w2a, *b2a;
    float *w1o, *w2o;   // w1o: [n][16][HW] buffer, k stored in ch 0..8
};

__global__ __launch_bounds__(256, 4) void k_weights(WParams P)
{
    __shared__ float ls1[18], lt1[18], lw1a[288];
    __shared__ float ls2[16], lt2[16], lw1b[16];
    __shared__ float ls3[16], lt3[16], lw2a[16];
    __shared__ float lwp[4], lsc[2];

    int t = threadIdx.x;
    if (t < 18) {
        float sc = P.bn1g[t] * rsqrtf(P.bn1v[t] + 1e-5f);
        ls1[t] = sc; lt1[t] = P.bn1b[t] - P.bn1m[t] * sc;
    } else if (t >= 32 && t < 48) {
        int c = t - 32;
        float sc = P.bn2g[c] * rsqrtf(P.bn2v[c] + 1e-5f);
        ls2[c] = sc; lt2[c] = P.bn2b[c] - P.bn2m[c] * sc; lw1b[c] = P.w1b[c];
    } else if (t >= 64 && t < 80) {
        int c = t - 64;
        float sc = P.bn3g[c] * rsqrtf(P.bn3v[c] + 1e-5f);
        ls3[c] = sc; lt3[c] = P.bn3b[c] - P.bn3m[c] * sc; lw2a[c] = P.w2a[c];
    } else if (t >= 96 && t < 100) {
        lwp[t - 96] = P.wp[t - 96];
    } else if (t == 100) {
        lsc[0] = P.b1b[0]; lsc[1] = P.b2a[0];
    }
    for (int i = t; i < 288; i += 256) lw1a[i] = P.w1a[i];
    __syncthreads();

    int p = blockIdx.x * 256 + t;
    int n = p / HW_, s = p - n * HW_;
    int hi = s / W_, wi = s - hi * W_;

    float x1c[16], ggc[16];
#pragma unroll
    for (int c = 0; c < 16; c++) {
        x1c[c] = P.x1[(n * 16 + c) * HW_ + s];
        ggc[c] = P.gg[(n * 16 + c) * HW_ + s];
    }

    float w1r[9], w2r[9];

#pragma unroll
    for (int ki = 0; ki < 3; ki++) {
        int hn = hi + ki - 1; hn = (hn < 0) ? -hn : ((hn >= H_) ? 2 * (H_ - 1) - hn : hn);
        float dlh = (float)(hi - hn) * (2.0f / (H_ - 1));
#pragma unroll
        for (int kj = 0; kj < 3; kj++) {
            int k = ki * 3 + kj;
            int wn = wi + kj - 1; wn = (wn < 0) ? -wn : ((wn >= W_) ? 2 * (W_ - 1) - wn : wn);
            int snk = hn * W_ + wn;
            float dlw = (float)(wi - wn) * (2.0f / (W_ - 1));

            // prefetch neighbor values (independent loads batch together)
            float f2[16], f3[16];
#pragma unroll
            for (int c = 0; c < 16; c++) {
                f2[c] = P.x2[(n * 16 + c) * HW_ + snk];
                f3[c] = P.gg[(n * 16 + c) * HW_ + snk];
            }

            float h1[16];
#pragma unroll
            for (int o = 0; o < 16; o++) h1[o] = 0.0f;
#pragma unroll
            for (int c = 0; c < 16; c++) {
                float f = x1c[c] - f2[c];
                f = fmaxf(fmaf(f, ls1[c], lt1[c]), 0.0f);
#pragma unroll
                for (int o = 0; o < 16; o++) h1[o] = fmaf(lw1a[o * 18 + c], f, h1[o]);
            }
#pragma unroll
            for (int pc = 0; pc < 2; pc++) {
                float f = lwp[pc * 2 + 0] * dlw + lwp[pc * 2 + 1] * dlh;
                f = fmaxf(fmaf(f, ls1[16 + pc], lt1[16 + pc]), 0.0f);
#pragma unroll
                for (int o = 0; o < 16; o++) h1[o] = fmaf(lw1a[o * 18 + 16 + pc], f, h1[o]);
            }
            float l1 = lsc[0];
#pragma unroll
            for (int o = 0; o < 16; o++) {
                float v = fmaxf(fmaf(h1[o], ls2[o], lt2[o]), 0.0f);
                l1 = fmaf(lw1b[o], v, l1);
            }
            w1r[k] = l1;

            float l2 = lsc[1];
#pragma unroll
            for (int c = 0; c < 16; c++) {
                float f = ggc[c] - f3[c];
                f = fmaxf(fmaf(f, ls3[c], lt3[c]), 0.0f);
                l2 = fmaf(lw2a[c], f, l2);
            }
            w2r[k] = l2;
        }
    }

    float m1 = w1r[0], m2 = w2r[0];
#pragma unroll
    for (int k = 1; k < 9; k++) { m1 = fmaxf(m1, w1r[k]); m2 = fmaxf(m2, w2r[k]); }
    float sum1 = 0.0f, sum2 = 0.0f;
#pragma unroll
    for (int k = 0; k < 9; k++) {
        w1r[k] = __expf(w1r[k] - m1); sum1 += w1r[k];
        w2r[k] = __expf(w2r[k] - m2); sum2 += w2r[k];
    }
    float i1 = 1.0f / sum1, i2 = 1.0f / sum2;
#pragma unroll
    for (int k = 0; k < 9; k++) {
        P.w1o[(n * 16 + k) * HW_ + s] = w1r[k] * i1;   // stride-16 (aliases x1)
        P.w2o[(n * 9 + k) * HW_ + s]  = w2r[k] * i2;
    }
}

// ---------------------------------------------------------------------------
// K4: generic 9-tap weighted aggregation over reflected neighbors.
// dst[c,s] = sum_k w[(n*wstride+k)*HW+s] * src[c, sn[k]];  16 ch per thread.
// ---------------------------------------------------------------------------
__global__ __launch_bounds__(256) void k_agg(
    const float* __restrict__ src, const float* __restrict__ w, int wstride,
    float* __restrict__ dst)
{
    int p = blockIdx.x * 256 + threadIdx.x;
    int cb = blockIdx.y;
    int n = p / HW_, s = p - n * HW_;
    int hi = s / W_, wi = s - hi * W_;

    int sn[9];
#pragma unroll
    for (int ki = 0; ki < 3; ki++) {
        int hn = hi + ki - 1; hn = (hn < 0) ? -hn : ((hn >= H_) ? 2 * (H_ - 1) - hn : hn);
#pragma unroll
        for (int kj = 0; kj < 3; kj++) {
            int wn = wi + kj - 1; wn = (wn < 0) ? -wn : ((wn >= W_) ? 2 * (W_ - 1) - wn : wn);
            sn[ki * 3 + kj] = hn * W_ + wn;
        }
    }
    float wv[9];
#pragma unroll
    for (int k = 0; k < 9; k++) wv[k] = w[(n * wstride + k) * HW_ + s];

#pragma unroll
    for (int ci = 0; ci < 16; ci++) {
        int c = cb * 16 + ci;
        const float* sc_ = src + (n * 64 + c) * HW_;
        float a = 0.0f;
#pragma unroll
        for (int k = 0; k < 9; k++) a = fmaf(wv[k], sc_[sn[k]], a);
        dst[(n * 64 + c) * HW_ + s] = a;
    }
}

// ---------------------------------------------------------------------------
extern "C" void kernel_launch(void* const* d_in, const int* in_sizes, int n_in,
                              void* d_out, int out_size, void* d_ws, size_t ws_size,
                              hipStream_t stream)
{
    const float* x    = (const float*)d_in[0];
    const float* g    = (const float*)d_in[1];
    const float* w_q  = (const float*)d_in[2];
    const float* b_q  = (const float*)d_in[3];
    const float* w_k  = (const float*)d_in[4];
    const float* b_k  = (const float*)d_in[5];
    const float* w_v  = (const float*)d_in[6];
    const float* b_v  = (const float*)d_in[7];
    const float* w_g  = (const float*)d_in[8];
    const float* b_g  = (const float*)d_in[9];
    const float* w_p  = (const float*)d_in[10];
    // d_in[11] = b_p (cancels in center-minus-neighbor subtraction)
    const float* bn1g = (const float*)d_in[12];
    const float* bn1b = (const float*)d_in[13];
    const float* bn1m = (const float*)d_in[14];
    const float* bn1v = (const float*)d_in[15];
    const float* w1a  = (const float*)d_in[16];
    const float* bn2g = (const float*)d_in[17];
    const float* bn2b = (const float*)d_in[18];
    const float* bn2m = (const float*)d_in[19];
    const float* bn2v = (const float*)d_in[20];
    const float* w1b  = (const float*)d_in[21];
    const float* b1b  = (const float*)d_in[22];
    const float* bn3g = (const float*)d_in[23];
    const float* bn3b = (const float*)d_in[24];
    const float* bn3m = (const float*)d_in[25];
    const float* bn3v = (const float*)d_in[26];
    const float* w2a  = (const float*)d_in[27];
    const float* b2a  = (const float*)d_in[28];

    float* ws   = (float*)d_ws;
    float* x1   = ws;                       // 2*16*HW  (w1 aliases this)
    float* x2   = x1 + 2359296;             // 2*16*HW
    float* gg   = x2 + 2359296;             // 2*16*HW
    float* out1 = gg + 2359296;             // 2*64*HW
    float* w2b  = out1 + 9437184;           // 2*9*HW
    float* x3   = (float*)d_out;            // d_out doubles as x3 scratch

    k_proj_x<<<576, 256, 0, stream>>>(x, w_q, b_q, w_k, b_k, w_v, b_v, x1, x2, x3);
    k_proj_g<<<576, 256, 0, stream>>>(g, w_g, b_g, gg);

    WParams P;
    P.x1 = x1; P.x2 = x2; P.gg = gg;
    P.wp = w_p;
    P.bn1g = bn1g; P.bn1b = bn1b; P.bn1m = bn1m; P.bn1v = bn1v; P.w1a = w1a;
    P.bn2g = bn2g; P.bn2b = bn2b; P.bn2m = bn2m; P.bn2v = bn2v; P.w1b = w1b; P.b1b = b1b;
    P.bn3g = bn3g; P.bn3b = bn3b; P.bn3m = bn3m; P.bn3v = bn3v; P.w2a = w2a; P.b2a = b2a;
    P.w1o = x1;    // alias: each thread reads x1 at its own pixel first
    P.w2o = w2b;
    k_weights<<<576, 256, 0, stream>>>(P);

    k_agg<<<dim3(576, 4), 256, 0, stream>>>(x3, x1, 16, out1);    // agg1 (w1)
    k_agg<<<dim3(576, 4), 256, 0, stream>>>(out1, w2b, 9, (float*)d_out); // agg2 (w2)
}

// Round 3
// 281.985 us; speedup vs baseline: 4.0625x; 3.6701x over previous
//
#include <hip/hip_runtime.h>
#include <math.h>

#define H_ 192
#define W_ 384
#define HW_ 73728

// ---------------------------------------------------------------------------
// K1: x-projections.  x [2,64,H,W] -> x1,x2 [2,16,H,W], x3 [2,64,H,W]
// ---------------------------------------------------------------------------
__global__ __launch_bounds__(256) void k_proj_x(
    const float* __restrict__ x,
    const float* __restrict__ wq, const float* __restrict__ bq,
    const float* __restrict__ wk, const float* __restrict__ bk,
    const float* __restrict__ wv, const float* __restrict__ bv,
    float* __restrict__ x1, float* __restrict__ x2, float* __restrict__ x3)
{
    __shared__ float l[1024 + 1024 + 4096 + 96];
    float* lq  = l;
    float* lk  = l + 1024;
    float* lv  = l + 2048;
    float* lbq = l + 6144;
    float* lbk = l + 6160;
    float* lbv = l + 6176;
    for (int i = threadIdx.x; i < 1024; i += 256) { lq[i] = wq[i]; lk[i] = wk[i]; }
    for (int i = threadIdx.x; i < 4096; i += 256) { lv[i] = wv[i]; }
    if (threadIdx.x < 16) { lbq[threadIdx.x] = bq[threadIdx.x]; lbk[threadIdx.x] = bk[threadIdx.x]; }
    if (threadIdx.x < 64) { lbv[threadIdx.x] = bv[threadIdx.x]; }
    __syncthreads();

    int p = blockIdx.x * 256 + threadIdx.x;
    int n = p / HW_, s = p - n * HW_;

    float aq[16], ak[16], av[64];
#pragma unroll
    for (int o = 0; o < 16; o++) { aq[o] = lbq[o]; ak[o] = lbk[o]; }
#pragma unroll
    for (int o = 0; o < 64; o++) { av[o] = lbv[o]; }

    const float* xp = x + n * (64 * HW_) + s;
    for (int c = 0; c < 64; c++) {
        float xv = xp[c * HW_];
#pragma unroll
        for (int o = 0; o < 16; o++) {
            aq[o] = fmaf(lq[o * 64 + c], xv, aq[o]);
            ak[o] = fmaf(lk[o * 64 + c], xv, ak[o]);
        }
#pragma unroll
        for (int o = 0; o < 64; o++) {
            av[o] = fmaf(lv[o * 64 + c], xv, av[o]);
        }
    }
#pragma unroll
    for (int o = 0; o < 16; o++) {
        x1[(n * 16 + o) * HW_ + s] = aq[o];
        x2[(n * 16 + o) * HW_ + s] = ak[o];
    }
#pragma unroll
    for (int o = 0; o < 64; o++) {
        x3[(n * 64 + o) * HW_ + s] = av[o];
    }
}

// ---------------------------------------------------------------------------
// K2: g-projection.  g [2,128,H,W] -> gg [2,16,H,W]
// ---------------------------------------------------------------------------
__global__ __launch_bounds__(256) void k_proj_g(
    const float* __restrict__ g,
    const float* __restrict__ wg, const float* __restrict__ bg,
    float* __restrict__ gg)
{
    __shared__ float l[2048 + 16];
    for (int i = threadIdx.x; i < 2048; i += 256) l[i] = wg[i];
    if (threadIdx.x < 16) l[2048 + threadIdx.x] = bg[threadIdx.x];
    __syncthreads();

    int p = blockIdx.x * 256 + threadIdx.x;
    int n = p / HW_, s = p - n * HW_;

    float a[16];
#pragma unroll
    for (int o = 0; o < 16; o++) a[o] = l[2048 + o];

    const float* gp = g + n * (128 * HW_) + s;
    for (int c = 0; c < 128; c++) {
        float gv = gp[c * HW_];
#pragma unroll
        for (int o = 0; o < 16; o++) a[o] = fmaf(l[o * 128 + c], gv, a[o]);
    }
#pragma unroll
    for (int o = 0; o < 16; o++) gg[(n * 16 + o) * HW_ + s] = a[o];
}

// ---------------------------------------------------------------------------
// K3: tap-parallel weight logits. grid (576, 9): blockIdx.y = neighbor tap.
// Each thread computes UNNORMALIZED w1,w2 logits for one (pixel, tap).
// Live state ~ h1[16] + temporaries -> no spill.
// ---------------------------------------------------------------------------
struct WParams {
    const float *x1, *x2, *gg;
    const float *wp;
    const float *bn1g, *bn1b, *bn1m, *bn1v, *w1a;
    const float *bn2g, *bn2b, *bn2m, *bn2v, *w1b, *b1b;
    const float *bn3g, *bn3b, *bn3m, *bn3v, *w2a, *b2a;
    float *w1o, *w2o;   // [n][9][HW] raw logits
};

__global__ __launch_bounds__(256) void k_wtap(WParams P)
{
    __shared__ float ls1[18], lt1[18], lw1a[288];
    __shared__ float ls2[16], lt2[16], lw1b[16];
    __shared__ float ls3[16], lt3[16], lw2a[16];
    __shared__ float lwp[4], lsc[2];

    int t = threadIdx.x;
    if (t < 18) {
        float sc = P.bn1g[t] * rsqrtf(P.bn1v[t] + 1e-5f);
        ls1[t] = sc; lt1[t] = P.bn1b[t] - P.bn1m[t] * sc;
    } else if (t >= 32 && t < 48) {
        int c = t - 32;
        float sc = P.bn2g[c] * rsqrtf(P.bn2v[c] + 1e-5f);
        ls2[c] = sc; lt2[c] = P.bn2b[c] - P.bn2m[c] * sc; lw1b[c] = P.w1b[c];
    } else if (t >= 64 && t < 80) {
        int c = t - 64;
        float sc = P.bn3g[c] * rsqrtf(P.bn3v[c] + 1e-5f);
        ls3[c] = sc; lt3[c] = P.bn3b[c] - P.bn3m[c] * sc; lw2a[c] = P.w2a[c];
    } else if (t >= 96 && t < 100) {
        lwp[t - 96] = P.wp[t - 96];
    } else if (t == 100) {
        lsc[0] = P.b1b[0]; lsc[1] = P.b2a[0];
    }
    for (int i = t; i < 288; i += 256) lw1a[i] = P.w1a[i];
    __syncthreads();

    int k  = blockIdx.y;          // 0..8, uniform
    int ki = k / 3, kj = k - ki * 3;

    int p = blockIdx.x * 256 + t;
    int n = p / HW_, s = p - n * HW_;
    int hi = s / W_, wi = s - hi * W_;

    int hn = hi + ki - 1; hn = (hn < 0) ? -hn : ((hn >= H_) ? 2 * (H_ - 1) - hn : hn);
    int wn = wi + kj - 1; wn = (wn < 0) ? -wn : ((wn >= W_) ? 2 * (W_ - 1) - wn : wn);
    int snk = hn * W_ + wn;
    float dlh = (float)(hi - hn) * (2.0f / (H_ - 1));
    float dlw = (float)(wi - wn) * (2.0f / (W_ - 1));

    const float* x1p = P.x1 + n * (16 * HW_);
    const float* x2p = P.x2 + n * (16 * HW_);
    const float* ggp = P.gg + n * (16 * HW_);

    float h1[16];
#pragma unroll
    for (int o = 0; o < 16; o++) h1[o] = 0.0f;

#pragma unroll
    for (int c = 0; c < 16; c++) {
        float f = x1p[c * HW_ + s] - x2p[c * HW_ + snk];
        f = fmaxf(fmaf(f, ls1[c], lt1[c]), 0.0f);
#pragma unroll
        for (int o = 0; o < 16; o++) h1[o] = fmaf(lw1a[o * 18 + c], f, h1[o]);
    }
#pragma unroll
    for (int pc = 0; pc < 2; pc++) {
        float f = lwp[pc * 2 + 0] * dlw + lwp[pc * 2 + 1] * dlh;
        f = fmaxf(fmaf(f, ls1[16 + pc], lt1[16 + pc]), 0.0f);
#pragma unroll
        for (int o = 0; o < 16; o++) h1[o] = fmaf(lw1a[o * 18 + 16 + pc], f, h1[o]);
    }
    float l1 = lsc[0];
#pragma unroll
    for (int o = 0; o < 16; o++) {
        float v = fmaxf(fmaf(h1[o], ls2[o], lt2[o]), 0.0f);
        l1 = fmaf(lw1b[o], v, l1);
    }

    float l2 = lsc[1];
#pragma unroll
    for (int c = 0; c < 16; c++) {
        float f = ggp[c * HW_ + s] - ggp[c * HW_ + snk];
        f = fmaxf(fmaf(f, ls3[c], lt3[c]), 0.0f);
        l2 = fmaf(lw2a[c], f, l2);
    }

    P.w1o[(n * 9 + k) * HW_ + s] = l1;
    P.w2o[(n * 9 + k) * HW_ + s] = l2;
}

// ---------------------------------------------------------------------------
// K4: 9-tap weighted aggregation; softmax of the 9 raw logits done in-reg.
// grid (576, 4): blockIdx.y = 16-channel slab.
// ---------------------------------------------------------------------------
__global__ __launch_bounds__(256) void k_agg(
    const float* __restrict__ src, const float* __restrict__ wlog,
    float* __restrict__ dst)
{
    int p = blockIdx.x * 256 + threadIdx.x;
    int cb = blockIdx.y;
    int n = p / HW_, s = p - n * HW_;
    int hi = s / W_, wi = s - hi * W_;

    int sn[9];
#pragma unroll
    for (int ki = 0; ki < 3; ki++) {
        int hn = hi + ki - 1; hn = (hn < 0) ? -hn : ((hn >= H_) ? 2 * (H_ - 1) - hn : hn);
#pragma unroll
        for (int kj = 0; kj < 3; kj++) {
            int wn = wi + kj - 1; wn = (wn < 0) ? -wn : ((wn >= W_) ? 2 * (W_ - 1) - wn : wn);
            sn[ki * 3 + kj] = hn * W_ + wn;
        }
    }

    float wv[9];
#pragma unroll
    for (int k = 0; k < 9; k++) wv[k] = wlog[(n * 9 + k) * HW_ + s];
    float m = wv[0];
#pragma unroll
    for (int k = 1; k < 9; k++) m = fmaxf(m, wv[k]);
    float sum = 0.0f;
#pragma unroll
    for (int k = 0; k < 9; k++) { wv[k] = __expf(wv[k] - m); sum += wv[k]; }
    float inv = 1.0f / sum;
#pragma unroll
    for (int k = 0; k < 9; k++) wv[k] *= inv;

#pragma unroll
    for (int ci = 0; ci < 16; ci++) {
        int c = cb * 16 + ci;
        const float* sc_ = src + (n * 64 + c) * HW_;
        float a = 0.0f;
#pragma unroll
        for (int k = 0; k < 9; k++) a = fmaf(wv[k], sc_[sn[k]], a);
        dst[(n * 64 + c) * HW_ + s] = a;
    }
}

// ---------------------------------------------------------------------------
extern "C" void kernel_launch(void* const* d_in, const int* in_sizes, int n_in,
                              void* d_out, int out_size, void* d_ws, size_t ws_size,
                              hipStream_t stream)
{
    const float* x    = (const float*)d_in[0];
    const float* g    = (const float*)d_in[1];
    const float* w_q  = (const float*)d_in[2];
    const float* b_q  = (const float*)d_in[3];
    const float* w_k  = (const float*)d_in[4];
    const float* b_k  = (const float*)d_in[5];
    const float* w_v  = (const float*)d_in[6];
    const float* b_v  = (const float*)d_in[7];
    const float* w_g  = (const float*)d_in[8];
    const float* b_g  = (const float*)d_in[9];
    const float* w_p  = (const float*)d_in[10];
    // d_in[11] = b_p (cancels in center-minus-neighbor subtraction)
    const float* bn1g = (const float*)d_in[12];
    const float* bn1b = (const float*)d_in[13];
    const float* bn1m = (const float*)d_in[14];
    const float* bn1v = (const float*)d_in[15];
    const float* w1a  = (const float*)d_in[16];
    const float* bn2g = (const float*)d_in[17];
    const float* bn2b = (const float*)d_in[18];
    const float* bn2m = (const float*)d_in[19];
    const float* bn2v = (const float*)d_in[20];
    const float* w1b  = (const float*)d_in[21];
    const float* b1b  = (const float*)d_in[22];
    const float* bn3g = (const float*)d_in[23];
    const float* bn3b = (const float*)d_in[24];
    const float* bn3m = (const float*)d_in[25];
    const float* bn3v = (const float*)d_in[26];
    const float* w2a  = (const float*)d_in[27];
    const float* b2a  = (const float*)d_in[28];

    float* ws    = (float*)d_ws;
    float* x1    = ws;                     // 2*16*HW = 2359296 f
    float* x2    = x1 + 2359296;           // 2359296 f
    float* gg    = x2 + 2359296;           // 2359296 f
    float* out1  = gg + 2359296;           // 2*64*HW = 9437184 f
    float* w1log = out1 + 9437184;         // 2*9*HW = 1327104 f
    float* w2log = w1log + 1327104;        // 1327104 f   (total ~76.7 MB)
    float* x3    = (float*)d_out;          // d_out doubles as x3 scratch

    k_proj_x<<<576, 256, 0, stream>>>(x, w_q, b_q, w_k, b_k, w_v, b_v, x1, x2, x3);
    k_proj_g<<<576, 256, 0, stream>>>(g, w_g, b_g, gg);

    WParams P;
    P.x1 = x1; P.x2 = x2; P.gg = gg;
    P.wp = w_p;
    P.bn1g = bn1g; P.bn1b = bn1b; P.bn1m = bn1m; P.bn1v = bn1v; P.w1a = w1a;
    P.bn2g = bn2g; P.bn2b = bn2b; P.bn2m = bn2m; P.bn2v = bn2v; P.w1b = w1b; P.b1b = b1b;
    P.bn3g = bn3g; P.bn3b = bn3b; P.bn3m = bn3m; P.bn3v = bn3v; P.w2a = w2a; P.b2a = b2a;
    P.w1o = w1log; P.w2o = w2log;
    k_wtap<<<dim3(576, 9), 256, 0, stream>>>(P);

    k_agg<<<dim3(576, 4), 256, 0, stream>>>(x3, w1log, out1);            // agg1
    k_agg<<<dim3(576, 4), 256, 0, stream>>>(out1, w2log, (float*)d_out); // agg2
}